// Round 1
// baseline (451.347 us; speedup 1.0000x reference)
//
#include <hip/hip_runtime.h>
#include <cstdint>
#include <cstddef>

#define B 16
#define C 3
#define H 640
#define W 640
#define HW (H*W)            // 409600
#define NPIX 409            // int(H*W*0.001)
#define R 7                 // 15x15 patch radius

// ---- workspace layout (bytes) ----
#define TMP_OFF     0u
#define DARK_OFF    26214400u                    // B*H*W*4
#define HIST_OFF    52428800u                    // 2*B*H*W*4
#define CTRL_OFF    (HIST_OFF + 3u*16u*2048u*4u) // 3 hist levels
#define TIECNT_OFF  (CTRL_OFF + 1024u)
#define TIEOFF_OFF  (TIECNT_OFF + 16384u)
#define AMAX_OFF    (TIEOFF_OFF + 16384u)
#define FIN_OFF     (AMAX_OFF + 256u)
#define WS_NEED     (FIN_OFF + 512u)

static __device__ __forceinline__ float finf() { return __uint_as_float(0x7f800000u); }

// ---------------- K1 / K4: channel-min + horizontal 15-min ----------------
// SCALED=false: v = min_c(x[c])            (divide by 255 postponed -> monotone-exact)
// SCALED=true : v = min_c(x[c] / D2[c])    D2[c] = 255*(atmos[c]+1e-8)
template<bool SCALED>
__global__ void k_cmin_hmin(const float* __restrict__ x, float* __restrict__ tmp,
                            const float* __restrict__ fin) {
  const int bx = blockIdx.x, y = blockIdx.y, b = blockIdx.z;
  const int t = threadIdx.x;
  __shared__ float s[256 + 2*R];
  const float* xb = x + (size_t)b*C*HW + (size_t)y*W;
  float d0 = 1.f, d1 = 1.f, d2 = 1.f;
  if (SCALED) { d0 = fin[b*8+4]; d1 = fin[b*8+5]; d2 = fin[b*8+6]; }
  for (int i = t; i < 256 + 2*R; i += 256) {
    int col = bx*256 - R + i;
    float v = finf();
    if (col >= 0 && col < W) {
      float a0 = xb[col], a1 = xb[HW+col], a2 = xb[2*HW+col];
      if (SCALED) { a0 /= d0; a1 /= d1; a2 /= d2; }
      v = fminf(a0, fminf(a1, a2));
    }
    s[i] = v;
  }
  __syncthreads();
  const int xc = bx*256 + t;
  if (xc < W) {
    float m = s[t];
    #pragma unroll
    for (int j = 1; j < 15; ++j) m = fminf(m, s[t+j]);
    tmp[((size_t)b*H + y)*W + xc] = m;
  }
}

// ---------------- K2: vertical 15-min -> dark = m/255 ----------------
__global__ void k_vmin_dark(const float* __restrict__ tmp, float* __restrict__ dark) {
  const int idx = blockIdx.x*256 + threadIdx.x;
  if (idx >= B*HW) return;
  const int b = idx / HW, rem = idx - b*HW;
  const int y = rem / W, xc = rem - y*W;
  float m = finf();
  #pragma unroll
  for (int dy = -R; dy <= R; ++dy) {
    int yy = y + dy;
    if (yy >= 0 && yy < H) m = fminf(m, tmp[((size_t)b*H + yy)*W + xc]);
  }
  dark[idx] = m / 255.0f;   // monotone: bit-exact vs reference's min-of-(x/255)
}

// ---------------- radix-select histograms (fp32 bits, values in [0,1)) ----------------
template<int LEVEL>
__global__ void k_hist(const float* __restrict__ dark, unsigned int* __restrict__ hist,
                       const int* __restrict__ ctrl) {
  const int b = blockIdx.y, t = threadIdx.x;
  __shared__ unsigned int h[2048];
  for (int i = t; i < 2048; i += 256) h[i] = 0;
  __syncthreads();
  unsigned int pref = 0;
  if (LEVEL == 1) pref = (unsigned)ctrl[b*8+0];
  if (LEVEL == 2) pref = (unsigned)ctrl[b*8+2];
  const float* db = dark + (size_t)b*HW;
  for (int p = blockIdx.x*256 + t; p < HW; p += gridDim.x*256) {
    unsigned int bits = __float_as_uint(db[p]);
    if (LEVEL == 0)      atomicAdd(&h[bits >> 21], 1u);
    else if (LEVEL == 1) { if ((bits >> 21) == pref) atomicAdd(&h[(bits >> 10) & 0x7FFu], 1u); }
    else                 { if ((bits >> 10) == pref) atomicAdd(&h[bits & 0x3FFu], 1u); }
  }
  __syncthreads();
  unsigned int* gh = hist + ((size_t)LEVEL*B + b)*2048;
  for (int i = t; i < 2048; i += 256) if (h[i]) atomicAdd(&gh[i], h[i]);
}

__global__ void k_scan(const unsigned int* __restrict__ hist, int* __restrict__ ctrl, int level) {
  const int b = blockIdx.x, t = threadIdx.x;
  __shared__ unsigned int s[2048];
  __shared__ unsigned int ps[256];
  const unsigned int* h = hist + ((size_t)level*B + b)*2048;
  for (int i = t; i < 2048; i += 256) s[i] = h[i];
  __syncthreads();
  unsigned int sum = 0;
  #pragma unroll
  for (int k = 0; k < 8; ++k) sum += s[t*8 + k];
  ps[t] = sum;
  __syncthreads();
  if (t == 0) {
    int* cb = ctrl + b*8;
    int target = NPIX;
    if (level == 1) target = NPIX - cb[1];
    else if (level == 2) target = NPIX - cb[3];
    unsigned int above = 0; int group = 0;
    for (int g = 255; g >= 0; --g) {
      if (above + ps[g] >= (unsigned)target) { group = g; break; }
      above += ps[g];
    }
    int bin = group*8;
    for (int i = group*8 + 7; i >= group*8; --i) {
      if (above + s[i] >= (unsigned)target) { bin = i; break; }
      above += s[i];
    }
    if (level == 0)      { cb[0] = bin;                 cb[1] = (int)above; }
    else if (level == 1) { cb[2] = (cb[0] << 11) | bin; cb[3] = cb[1] + (int)above; }
    else { // exact threshold + tie budget K
      cb[4] = (cb[2] << 10) | bin;
      cb[5] = NPIX - (cb[3] + (int)above);
    }
  }
}

// ---------------- ordered tie selection (replicates stable top_k) ----------------
__global__ void k_tiecnt(const float* __restrict__ dark, const int* __restrict__ ctrl,
                         unsigned int* __restrict__ tieCnt) {
  const int b = blockIdx.y, blk = blockIdx.x, t = threadIdx.x;
  const unsigned int thr = (unsigned)ctrl[b*8+4];
  const float* db = dark + (size_t)b*HW;
  const int base = blk*1600;
  int cnt = 0;
  for (int j = 0; j < 7; ++j) {
    int o = j*256 + t;
    if (o < 1600) cnt += (__float_as_uint(db[base + o]) == thr);
  }
  __shared__ int red[256];
  red[t] = cnt; __syncthreads();
  for (int s2 = 128; s2 > 0; s2 >>= 1) { if (t < s2) red[t] += red[t + s2]; __syncthreads(); }
  if (t == 0) tieCnt[b*256 + blk] = (unsigned)red[0];
}

__global__ void k_tiescan(const unsigned int* __restrict__ tieCnt, unsigned int* __restrict__ tieOff) {
  const int b = blockIdx.x, t = threadIdx.x;
  __shared__ unsigned int s[256];
  s[t] = tieCnt[b*256 + t];
  __syncthreads();
  if (t == 0) {
    unsigned int run = 0;
    for (int i = 0; i < 256; ++i) { unsigned int v = s[i]; s[i] = run; run += v; }
  }
  __syncthreads();
  tieOff[b*256 + t] = s[t];
}

__global__ void k_select(const float* __restrict__ x, const float* __restrict__ dark,
                         const int* __restrict__ ctrl, const unsigned int* __restrict__ tieOff,
                         unsigned int* __restrict__ amax) {
  const int b = blockIdx.y, blk = blockIdx.x, t = threadIdx.x;
  const unsigned int thr = (unsigned)ctrl[b*8+4];
  const unsigned int K   = (unsigned)ctrl[b*8+5];
  const unsigned int myOff = tieOff[b*256 + blk];
  const float* db = dark + (size_t)b*HW;
  const float* xb = x + (size_t)b*C*HW;
  const int base = blk*1600;
  const int wave = t >> 6, lane = t & 63;
  __shared__ unsigned int wcnt[4];
  __shared__ unsigned int running;
  if (t == 0) running = 0;
  __syncthreads();
  for (int j = 0; j < 7; ++j) {
    int o = j*256 + t;
    bool valid = o < 1600;
    int p = base + o;
    unsigned int bits = valid ? __float_as_uint(db[p]) : 0u;
    bool gt = valid && (bits > thr);
    bool eq = valid && (bits == thr);
    if (gt) {  // raw-x max; /255 at the end is monotone-exact
      atomicMax(&amax[b*4+0], __float_as_uint(xb[p]));
      atomicMax(&amax[b*4+1], __float_as_uint(xb[HW + p]));
      atomicMax(&amax[b*4+2], __float_as_uint(xb[2*HW + p]));
    }
    unsigned long long m = __ballot(eq);
    if (lane == 0) wcnt[wave] = (unsigned)__popcll(m);
    __syncthreads();
    if (eq) {
      unsigned int pr = running;
      for (int w2 = 0; w2 < wave; ++w2) pr += wcnt[w2];
      pr += (unsigned)__popcll(m & ((1ull << lane) - 1ull));
      unsigned int rank = myOff + pr;
      if (rank < K) {
        atomicMax(&amax[b*4+0], __float_as_uint(xb[p]));
        atomicMax(&amax[b*4+1], __float_as_uint(xb[HW + p]));
        atomicMax(&amax[b*4+2], __float_as_uint(xb[2*HW + p]));
      }
    }
    __syncthreads();
    if (t == 0) running += wcnt[0] + wcnt[1] + wcnt[2] + wcnt[3];
    __syncthreads();
  }
}

__global__ void k_fin(const unsigned int* __restrict__ amax, float* __restrict__ fin) {
  const int t = threadIdx.x;
  if (t < B*C) {
    int b = t / 3, c = t - 3*b;
    float a = __uint_as_float(amax[b*4 + c]) / 255.0f;   // atmos = max(x)/255, bit-exact
    fin[b*8 + c]     = a;                                 // A[c]
    fin[b*8 + 4 + c] = 255.0f * (a + 1e-8f);              // D2[c]
  }
}

// ---------------- K5: vertical 15-min on scaled tile + recovery ----------------
__global__ void k_final(const float* __restrict__ x, const float* __restrict__ tmp,
                        const float* __restrict__ fin, float* __restrict__ out) {
  const int idx = blockIdx.x*256 + threadIdx.x;
  if (idx >= B*HW) return;
  const int b = idx / HW, rem = idx - b*HW;
  const int y = rem / W, xc = rem - y*W;
  float m = finf();
  #pragma unroll
  for (int dy = -R; dy <= R; ++dy) {
    int yy = y + dy;
    if (yy >= 0 && yy < H) m = fminf(m, tmp[((size_t)b*H + yy)*W + xc]);
  }
  const float tt = fmaxf(1.0f - 0.95f*m, 0.1f);
  const float A0 = fin[b*8+0], A1 = fin[b*8+1], A2 = fin[b*8+2];
  const size_t px = (size_t)b*C*HW + (size_t)rem;
  {
    float xn = x[px] / 255.0f;
    float r = (xn - A0)/tt + A0;
    out[px] = fminf(fmaxf(r, 0.0f), 1.0f) * 255.0f;
  }
  {
    float xn = x[px + HW] / 255.0f;
    float r = (xn - A1)/tt + A1;
    out[px + HW] = fminf(fmaxf(r, 0.0f), 1.0f) * 255.0f;
  }
  {
    float xn = x[px + 2*HW] / 255.0f;
    float r = (xn - A2)/tt + A2;
    out[px + 2*HW] = fminf(fmaxf(r, 0.0f), 1.0f) * 255.0f;
  }
}

extern "C" void kernel_launch(void* const* d_in, const int* in_sizes, int n_in,
                              void* d_out, int out_size, void* d_ws, size_t ws_size,
                              hipStream_t stream) {
  const float* x = (const float*)d_in[0];
  float* out = (float*)d_out;
  char* ws = (char*)d_ws;
  float* tmp            = (float*)(ws + TMP_OFF);
  float* dark           = (float*)(ws + DARK_OFF);
  unsigned int* hist    = (unsigned int*)(ws + HIST_OFF);
  int* ctrl             = (int*)(ws + CTRL_OFF);
  unsigned int* tieCnt  = (unsigned int*)(ws + TIECNT_OFF);
  unsigned int* tieOff  = (unsigned int*)(ws + TIEOFF_OFF);
  unsigned int* amax    = (unsigned int*)(ws + AMAX_OFF);
  float* fin            = (float*)(ws + FIN_OFF);

  // zero hist/ctrl/tie/amax/fin region (ws is poisoned 0xAA before every call)
  hipMemsetAsync(ws + HIST_OFF, 0, WS_NEED - HIST_OFF, stream);

  const dim3 g1(3, H, B);       // 3 col-blocks x 640 rows x 16 batches
  const dim3 gh(64, B);
  const dim3 gs(256, B);
  const int nflat = (B*HW + 255) / 256;   // 25600

  k_cmin_hmin<false><<<g1, 256, 0, stream>>>(x, tmp, nullptr);
  k_vmin_dark<<<nflat, 256, 0, stream>>>(tmp, dark);
  k_hist<0><<<gh, 256, 0, stream>>>(dark, hist, ctrl);
  k_scan<<<B, 256, 0, stream>>>(hist, ctrl, 0);
  k_hist<1><<<gh, 256, 0, stream>>>(dark, hist, ctrl);
  k_scan<<<B, 256, 0, stream>>>(hist, ctrl, 1);
  k_hist<2><<<gh, 256, 0, stream>>>(dark, hist, ctrl);
  k_scan<<<B, 256, 0, stream>>>(hist, ctrl, 2);
  k_tiecnt<<<gs, 256, 0, stream>>>(dark, ctrl, tieCnt);
  k_tiescan<<<B, 256, 0, stream>>>(tieCnt, tieOff);
  k_select<<<gs, 256, 0, stream>>>(x, dark, ctrl, tieOff, amax);
  k_fin<<<1, 64, 0, stream>>>(amax, fin);
  k_cmin_hmin<true><<<g1, 256, 0, stream>>>(x, tmp, fin);
  k_final<<<nflat, 256, 0, stream>>>(x, tmp, fin, out);
}

// Round 4
// 330.727 us; speedup vs baseline: 1.3647x; 1.3647x over previous
//
#include <hip/hip_runtime.h>
#include <cstdint>
#include <cstddef>

#define B 16
#define H 640
#define W 640
#define HW (H*W)            // 409600
#define NPIX 409            // int(H*W*0.001)
#define TS 64               // output tile
#define HT 78               // TS + 14 halo

// ---- workspace layout (bytes) ----
#define DARK_OFF   0u
#define HIST_OFF   26214400u                      // B*HW*4
#define CTRL_OFF   (HIST_OFF + 3u*16u*2048u*4u)   // 3 hist levels = 393216
#define TIECNT_OFF (CTRL_OFF + 512u)              // 16*8 ints ctrl
#define TIEOFF_OFF (TIECNT_OFF + 16384u)          // 16*256 uints
#define AMAX_OFF   (TIEOFF_OFF + 16384u)
#define FIN_OFF    (AMAX_OFF + 256u)
#define WS_END     (FIN_OFF + 512u)
#define ZERO_BYTES (WS_END - HIST_OFF)            // hist..fin zeroed per call

// ============ fused cmin + 15x15 minpool tile kernel ============
// MODE 0: dark = minpool(min_c(x))/255 -> store + plain LDS hist0 -> global atomics
// MODE 1: t = max(1-0.95*minpool(min_c(x*inv)),0.1); fused recovery -> out
template<int MODE>
__global__ __launch_bounds__(256) void k_pool(
    const float* __restrict__ x, float* __restrict__ dark,
    unsigned* __restrict__ hist, const float* __restrict__ fin,
    float* __restrict__ out)
{
  __shared__ float s1[HT*HT];   // 24336 B
  __shared__ float s2[HT*TS];   // 19968 B
  const int t = threadIdx.x;
  const int bx = blockIdx.x, by = blockIdx.y, b = blockIdx.z;
  const int x0 = bx*TS, y0 = by*TS;
  const float* xb = x + (size_t)b*3*HW;
  float i0=0.f,i1=0.f,i2=0.f, A0=0.f,A1=0.f,A2=0.f;
  if (MODE==1) {
    A0 = fin[b*8+0]; A1 = fin[b*8+1]; A2 = fin[b*8+2];
    i0 = fin[b*8+4]; i1 = fin[b*8+5]; i2 = fin[b*8+6];   // 1/(255*(A+1e-8))
  }
  const bool interior = (bx>0) & (bx<9) & (by>0) & (by<9);
  // phase 1: channel-min (optionally scaled) into s1 with halo
  if (interior) {
    for (int i=t;i<HT*HT;i+=256) {
      int ly=i/HT, lx=i-ly*HT;
      size_t p = (size_t)(y0-7+ly)*W + (size_t)(x0-7+lx);
      float a0=xb[p], a1=xb[HW+p], a2=xb[2*HW+p];
      if (MODE==1){a0*=i0;a1*=i1;a2*=i2;}
      s1[i] = fminf(a0,fminf(a1,a2));
    }
  } else {
    for (int i=t;i<HT*HT;i+=256) {
      int ly=i/HT, lx=i-ly*HT;
      int gy=y0-7+ly, gx=x0-7+lx;
      float v = __uint_as_float(0x7f800000u);  // +inf pad
      if (gy>=0 && gy<H && gx>=0 && gx<W) {
        size_t p=(size_t)gy*W+(size_t)gx;
        float a0=xb[p], a1=xb[HW+p], a2=xb[2*HW+p];
        if (MODE==1){a0*=i0;a1*=i1;a2*=i2;}
        v = fminf(a0,fminf(a1,a2));
      }
      s1[i]=v;
    }
  }
  __syncthreads();
  // phase 2: horizontal 15-min (78 rows x 64 cols)
  for (int i=t;i<HT*TS;i+=256) {
    int ly=i>>6, lx=i&63;
    const float* r = s1 + ly*HT + lx;
    float m=r[0];
#pragma unroll
    for (int j=1;j<15;++j) m=fminf(m,r[j]);
    s2[ly*TS+lx]=m;
  }
  __syncthreads();
  unsigned* hl = (unsigned*)s1;   // s1 free after phase 2
  if (MODE==0) {
    for (int i=t;i<2048;i+=256) hl[i]=0u;
    __syncthreads();
  }
  // phase 3: vertical 15-min + epilogue (16 outputs/thread)
  for (int i=t;i<TS*TS;i+=256) {
    int oy=i>>6, ox=i&63;
    const float* c = s2 + oy*TS + ox;
    float m=c[0];
#pragma unroll
    for (int j=1;j<15;++j) m=fminf(m,c[j*TS]);
    if (MODE==0) {
      float d = m/255.0f;   // exact div: selection space must match reference bits
      dark[(size_t)b*HW + (size_t)(y0+oy)*W + (size_t)(x0+ox)] = d;
      atomicAdd(&hl[__float_as_uint(d)>>21], 1u);
    } else {
      float tt = fmaxf(1.0f - 0.95f*m, 0.1f);
      float rt = 1.0f/tt;
      size_t p = (size_t)(y0+oy)*W + (size_t)(x0+ox);
      const float inv255 = 1.0f/255.0f;
      float r0 = (xb[p]*inv255      - A0)*rt + A0;
      float r1 = (xb[HW+p]*inv255   - A1)*rt + A1;
      float r2 = (xb[2*HW+p]*inv255 - A2)*rt + A2;
      float* ob = out + (size_t)b*3*HW;
      ob[p]      = fminf(fmaxf(r0,0.f),1.f)*255.0f;
      ob[HW+p]   = fminf(fmaxf(r1,0.f),1.f)*255.0f;
      ob[2*HW+p] = fminf(fmaxf(r2,0.f),1.f)*255.0f;
    }
  }
  if (MODE==0) {
    __syncthreads();
    unsigned* gh = hist + (size_t)b*2048;
    for (int i=t;i<2048;i+=256){ unsigned v=hl[i]; if (v) atomicAdd(&gh[i], v); }
  }
}

// ============ per-batch radix pick at one level (round-1 verbatim) ============
__global__ void k_scan(const unsigned int* __restrict__ hist, int* __restrict__ ctrl, int level) {
  const int b = blockIdx.x, t = threadIdx.x;
  __shared__ unsigned int s[2048];
  __shared__ unsigned int ps[256];
  const unsigned int* h = hist + ((size_t)level*B + b)*2048;
  for (int i = t; i < 2048; i += 256) s[i] = h[i];
  __syncthreads();
  unsigned int sum = 0;
  #pragma unroll
  for (int k = 0; k < 8; ++k) sum += s[t*8 + k];
  ps[t] = sum;
  __syncthreads();
  if (t == 0) {
    int* cb = ctrl + b*8;
    int target = NPIX;
    if (level == 1) target = NPIX - cb[1];
    else if (level == 2) target = NPIX - cb[3];
    unsigned int above = 0; int group = 0;
    for (int g = 255; g >= 0; --g) {
      if (above + ps[g] >= (unsigned)target) { group = g; break; }
      above += ps[g];
    }
    int bin = group*8;
    for (int i = group*8 + 7; i >= group*8; --i) {
      if (above + s[i] >= (unsigned)target) { bin = i; break; }
      above += s[i];
    }
    if (level == 0)      { cb[0] = bin;                 cb[1] = (int)above; }
    else if (level == 1) { cb[2] = (cb[0] << 11) | bin; cb[3] = cb[1] + (int)above; }
    else { // exact threshold + tie budget K
      cb[4] = (cb[2] << 10) | bin;
      cb[5] = NPIX - (cb[3] + (int)above);
    }
  }
}

// ============ radix hist levels 1/2 (uint4 reads) ============
template<int LEVEL>
__global__ __launch_bounds__(256) void k_lvl(
    const float* __restrict__ dark, unsigned* __restrict__ hist,
    const int* __restrict__ ctrl)
{
  __shared__ unsigned hl[2048];
  const int t=threadIdx.x, b=blockIdx.y;
  for (int i=t;i<2048;i+=256) hl[i]=0u;
  const unsigned pref = (unsigned)ctrl[b*8 + (LEVEL==1?0:2)];
  __syncthreads();
  const uint4* db = (const uint4*)(dark + (size_t)b*HW) + (size_t)blockIdx.x*1600;
  for (int o=t;o<1600;o+=256) {
    uint4 v = db[o];
    unsigned w;
    w=v.x; if (LEVEL==1){ if((w>>21)==pref) atomicAdd(&hl[(w>>10)&0x7FFu],1u);} else { if((w>>10)==pref) atomicAdd(&hl[w&0x3FFu],1u);}
    w=v.y; if (LEVEL==1){ if((w>>21)==pref) atomicAdd(&hl[(w>>10)&0x7FFu],1u);} else { if((w>>10)==pref) atomicAdd(&hl[w&0x3FFu],1u);}
    w=v.z; if (LEVEL==1){ if((w>>21)==pref) atomicAdd(&hl[(w>>10)&0x7FFu],1u);} else { if((w>>10)==pref) atomicAdd(&hl[w&0x3FFu],1u);}
    w=v.w; if (LEVEL==1){ if((w>>21)==pref) atomicAdd(&hl[(w>>10)&0x7FFu],1u);} else { if((w>>10)==pref) atomicAdd(&hl[w&0x3FFu],1u);}
  }
  __syncthreads();
  unsigned* gh = hist + ((size_t)LEVEL*16 + (size_t)b)*2048;
  for (int i=t;i<2048;i+=256){ unsigned v=hl[i]; if (v) atomicAdd(&gh[i], v); }
}

// ============ tie machinery (round-1 verbatim: proven deterministic) ============
__global__ void k_tiecnt(const float* __restrict__ dark, const int* __restrict__ ctrl,
                         unsigned int* __restrict__ tieCnt) {
  const int b = blockIdx.y, blk = blockIdx.x, t = threadIdx.x;
  const unsigned int thr = (unsigned)ctrl[b*8+4];
  const float* db = dark + (size_t)b*HW;
  const int base = blk*1600;
  int cnt = 0;
  for (int j = 0; j < 7; ++j) {
    int o = j*256 + t;
    if (o < 1600) cnt += (__float_as_uint(db[base + o]) == thr);
  }
  __shared__ int red[256];
  red[t] = cnt; __syncthreads();
  for (int s2 = 128; s2 > 0; s2 >>= 1) { if (t < s2) red[t] += red[t + s2]; __syncthreads(); }
  if (t == 0) tieCnt[b*256 + blk] = (unsigned)red[0];
}

__global__ void k_tiescan(const unsigned int* __restrict__ tieCnt, unsigned int* __restrict__ tieOff) {
  const int b = blockIdx.x, t = threadIdx.x;
  __shared__ unsigned int s[256];
  s[t] = tieCnt[b*256 + t];
  __syncthreads();
  if (t == 0) {
    unsigned int run = 0;
    for (int i = 0; i < 256; ++i) { unsigned int v = s[i]; s[i] = run; run += v; }
  }
  __syncthreads();
  tieOff[b*256 + t] = s[t];
}

__global__ void k_select(const float* __restrict__ x, const float* __restrict__ dark,
                         const int* __restrict__ ctrl, const unsigned int* __restrict__ tieOff,
                         unsigned int* __restrict__ amax) {
  const int b = blockIdx.y, blk = blockIdx.x, t = threadIdx.x;
  const unsigned int thr = (unsigned)ctrl[b*8+4];
  const unsigned int K   = (unsigned)ctrl[b*8+5];
  const unsigned int myOff = tieOff[b*256 + blk];
  const float* db = dark + (size_t)b*HW;
  const float* xb = x + (size_t)b*3*HW;
  const int base = blk*1600;
  const int wave = t >> 6, lane = t & 63;
  __shared__ unsigned int wcnt[4];
  __shared__ unsigned int running;
  if (t == 0) running = 0;
  __syncthreads();
  for (int j = 0; j < 7; ++j) {
    int o = j*256 + t;
    bool valid = o < 1600;
    int p = base + o;
    unsigned int bits = valid ? __float_as_uint(db[p]) : 0u;
    bool gt = valid && (bits > thr);
    bool eq = valid && (bits == thr);
    if (gt) {  // raw-x max; /255 at the end is monotone-exact
      atomicMax(&amax[b*4+0], __float_as_uint(xb[p]));
      atomicMax(&amax[b*4+1], __float_as_uint(xb[HW + p]));
      atomicMax(&amax[b*4+2], __float_as_uint(xb[2*HW + p]));
    }
    unsigned long long m = __ballot(eq);
    if (lane == 0) wcnt[wave] = (unsigned)__popcll(m);
    __syncthreads();
    if (eq) {
      unsigned int pr = running;
      for (int w2 = 0; w2 < wave; ++w2) pr += wcnt[w2];
      pr += (unsigned)__popcll(m & ((1ull << lane) - 1ull));
      unsigned int rank = myOff + pr;
      if (rank < K) {
        atomicMax(&amax[b*4+0], __float_as_uint(xb[p]));
        atomicMax(&amax[b*4+1], __float_as_uint(xb[HW + p]));
        atomicMax(&amax[b*4+2], __float_as_uint(xb[2*HW + p]));
      }
    }
    __syncthreads();
    if (t == 0) running += wcnt[0] + wcnt[1] + wcnt[2] + wcnt[3];
    __syncthreads();
  }
}

__global__ void k_fin(const unsigned int* __restrict__ amax, float* __restrict__ fin) {
  const int t = threadIdx.x;
  if (t < B*3) {
    int b = t / 3, c = t - 3*b;
    float a = __uint_as_float(amax[b*4 + c]) / 255.0f;   // atmos = max(x)/255, bit-exact
    fin[b*8 + c]     = a;                                 // A[c]
    fin[b*8 + 4 + c] = 1.0f/(255.0f*(a + 1e-8f));         // 1/(255*(A+1e-8))
  }
}

extern "C" void kernel_launch(void* const* d_in, const int* in_sizes, int n_in,
                              void* d_out, int out_size, void* d_ws, size_t ws_size,
                              hipStream_t stream) {
  (void)in_sizes; (void)n_in; (void)out_size; (void)ws_size;
  const float* x = (const float*)d_in[0];
  float* out = (float*)d_out;
  char* ws = (char*)d_ws;
  float*    dark   = (float*)(ws + DARK_OFF);
  unsigned* hist   = (unsigned*)(ws + HIST_OFF);
  int*      ctrl   = (int*)(ws + CTRL_OFF);
  unsigned* tieCnt = (unsigned*)(ws + TIECNT_OFF);
  unsigned* tieOff = (unsigned*)(ws + TIEOFF_OFF);
  unsigned* amax   = (unsigned*)(ws + AMAX_OFF);
  float*    fin    = (float*)(ws + FIN_OFF);

  hipMemsetAsync(ws + HIST_OFF, 0, ZERO_BYTES, stream);

  const dim3 gt2(10, 10, B);
  const dim3 gl(64, B);
  const dim3 gs(256, B);

  k_pool<0><<<gt2, 256, 0, stream>>>(x, dark, hist, nullptr, nullptr);
  k_scan<<<B, 256, 0, stream>>>(hist, ctrl, 0);
  k_lvl<1><<<gl, 256, 0, stream>>>(dark, hist, ctrl);
  k_scan<<<B, 256, 0, stream>>>(hist, ctrl, 1);
  k_lvl<2><<<gl, 256, 0, stream>>>(dark, hist, ctrl);
  k_scan<<<B, 256, 0, stream>>>(hist, ctrl, 2);
  k_tiecnt<<<gs, 256, 0, stream>>>(dark, ctrl, tieCnt);
  k_tiescan<<<B, 256, 0, stream>>>(tieCnt, tieOff);
  k_select<<<gs, 256, 0, stream>>>(x, dark, ctrl, tieOff, amax);
  k_fin<<<1, 64, 0, stream>>>(amax, fin);
  k_pool<1><<<gt2, 256, 0, stream>>>(x, nullptr, nullptr, fin, out);
}

// Round 5
// 321.688 us; speedup vs baseline: 1.4031x; 1.0281x over previous
//
#include <hip/hip_runtime.h>
#include <cstdint>
#include <cstddef>

#define B 16
#define H 640
#define W 640
#define HW (H*W)            // 409600
#define NPIX 409            // int(H*W*0.001)
#define TSX 64
#define TSY 40              // 640/40=16 exact; LDS 30.7KB -> 5 blocks/CU
#define HTX 78              // TSX+14
#define HTY 54              // TSY+14

// ---- workspace layout (bytes) ----
#define DARK_OFF   0u
#define HIST_OFF   26214400u                      // B*HW*4
#define AMAX_OFF   (HIST_OFF + 393216u)           // 3*16*2048*4
#define CTRL_OFF   (AMAX_OFF + 256u)
#define TIECNT_OFF (CTRL_OFF + 512u)
#define TIEOFF_OFF (TIECNT_OFF + 16384u)
#define ZERO_BYTES (393216u + 256u)               // hist + amax only

// ---- parallel "pick bin with suffix count >= target" (round-1 semantics) ----
// counts in hl[nb]; returns bin + above (count strictly above bin). All threads
// of the block get the same result. Ends with __syncthreads (hl reusable after).
__device__ __forceinline__ void pick_bin(const unsigned* __restrict__ hl, unsigned* ps,
                                         unsigned* sgab, int nb, unsigned target,
                                         int& bin_out, unsigned& above_out) {
  const int t = threadIdx.x;
  const int per = nb >> 8;
  unsigned own = 0;
  for (int k = 0; k < per; ++k) own += hl[t*per + k];
  ps[t] = own;
  __syncthreads();
  for (int off = 1; off < 256; off <<= 1) {      // inclusive suffix sum
    unsigned v = (t + off < 256) ? ps[t + off] : 0u;
    __syncthreads();
    ps[t] += v;
    __syncthreads();
  }
  unsigned incl = ps[t];
  if (incl >= target && incl - own < target) { sgab[0] = (unsigned)t; sgab[1] = incl - own; }
  __syncthreads();
  const int g = (int)sgab[0];
  unsigned above = sgab[1];
  int bin = g*per;
  for (int i = g*per + per - 1; i >= g*per; --i) {   // redundant identical compute
    unsigned c = hl[i];
    if (above + c >= target) { bin = i; break; }
    above += c;
  }
  bin_out = bin; above_out = above;
  __syncthreads();
}

// ============ fused cmin + 15x15 minpool tile kernel ============
// MODE 0: dark = minpool(min_c(x))/255 -> store + LDS hist0 -> global atomics
// MODE 1: t = max(1-0.95*minpool(min_c(x*inv)),0.1); fused recovery -> out
template<int MODE>
__global__ __launch_bounds__(256) void k_pool(
    const float* __restrict__ x, float* __restrict__ dark,
    unsigned* __restrict__ hist, const unsigned* __restrict__ amax,
    float* __restrict__ out)
{
  __shared__ float s1[HTY*HTX];   // 16848 B
  __shared__ float s2[HTY*TSX];   // 13824 B
  const int t = threadIdx.x;
  const int bx = blockIdx.x, by = blockIdx.y, b = blockIdx.z;
  const int x0 = bx*TSX, y0 = by*TSY;
  const float* xb = x + (size_t)b*3*HW;
  float i0=0.f,i1=0.f,i2=0.f, A0=0.f,A1=0.f,A2=0.f;
  if (MODE==1) {
    A0 = __uint_as_float(amax[b*4+0]) / 255.0f;   // exact: matches max(x/255) bits
    A1 = __uint_as_float(amax[b*4+1]) / 255.0f;
    A2 = __uint_as_float(amax[b*4+2]) / 255.0f;
    i0 = 1.0f/(255.0f*(A0+1e-8f));
    i1 = 1.0f/(255.0f*(A1+1e-8f));
    i2 = 1.0f/(255.0f*(A2+1e-8f));
  }
  const bool interior = (bx>=1)&(bx<=8)&(by>=1)&(by<=14);
  // phase 1: channel-min (optionally scaled) into s1 with halo
  if (interior) {
    for (int i=t;i<HTY*HTX;i+=256) {
      int ly=i/HTX, lx=i-ly*HTX;
      size_t p = (size_t)(y0-7+ly)*W + (size_t)(x0-7+lx);
      float a0=xb[p], a1=xb[HW+p], a2=xb[2*HW+p];
      if (MODE==1){a0*=i0;a1*=i1;a2*=i2;}
      s1[i] = fminf(a0,fminf(a1,a2));
    }
  } else {
    for (int i=t;i<HTY*HTX;i+=256) {
      int ly=i/HTX, lx=i-ly*HTX;
      int gy=y0-7+ly, gx=x0-7+lx;
      float v = __uint_as_float(0x7f800000u);  // +inf pad
      if (gy>=0 && gy<H && gx>=0 && gx<W) {
        size_t p=(size_t)gy*W+(size_t)gx;
        float a0=xb[p], a1=xb[HW+p], a2=xb[2*HW+p];
        if (MODE==1){a0*=i0;a1*=i1;a2*=i2;}
        v = fminf(a0,fminf(a1,a2));
      }
      s1[i]=v;
    }
  }
  __syncthreads();
  // phase 2: horizontal 15-min (54 rows x 64 cols)
  for (int i=t;i<HTY*TSX;i+=256) {
    int ly=i>>6, lx=i&63;
    const float* r = s1 + ly*HTX + lx;
    float m=r[0];
#pragma unroll
    for (int j=1;j<15;++j) m=fminf(m,r[j]);
    s2[i]=m;            // i == ly*64+lx
  }
  __syncthreads();
  unsigned* hl = (unsigned*)s1;   // s1 free after phase 2
  if (MODE==0) {
    for (int i=t;i<2048;i+=256) hl[i]=0u;
    __syncthreads();
  }
  // phase 3: vertical 15-min + epilogue (2560 items = 10 full 256-iters)
  for (int i=t;i<TSY*TSX;i+=256) {
    int oy=i>>6, ox=i&63;
    const float* c = s2 + i;
    float m=c[0];
#pragma unroll
    for (int j=1;j<15;++j) m=fminf(m,c[j*TSX]);
    if (MODE==0) {
      float d = m/255.0f;   // exact div: selection space must match reference bits
      dark[(size_t)b*HW + (size_t)(y0+oy)*W + (size_t)(x0+ox)] = d;
      unsigned bin = __float_as_uint(d)>>21;
      // wave run-length aggregation (dark is plateau-constant along rows);
      // all lanes valid every iteration (2560 % 256 == 0)
      int lane = t & 63;
      unsigned pb = __shfl_up(bin, 1);
      bool leader = (lane==0) || (pb != bin);
      unsigned long long lm = __ballot(leader);
      if (leader) {
        unsigned long long higher = (lane==63) ? 0ull : (lm>>(lane+1));
        int len = higher ? __ffsll((long long)higher) : (64-lane);
        atomicAdd(&hl[bin], (unsigned)len);
      }
    } else {
      float tt = fmaxf(1.0f - 0.95f*m, 0.1f);
      float rt = 1.0f/tt;
      size_t p = (size_t)(y0+oy)*W + (size_t)(x0+ox);
      const float inv255 = 1.0f/255.0f;
      float r0 = (xb[p]*inv255      - A0)*rt + A0;
      float r1 = (xb[HW+p]*inv255   - A1)*rt + A1;
      float r2 = (xb[2*HW+p]*inv255 - A2)*rt + A2;
      float* ob = out + (size_t)b*3*HW;
      ob[p]      = fminf(fmaxf(r0,0.f),1.f)*255.0f;
      ob[HW+p]   = fminf(fmaxf(r1,0.f),1.f)*255.0f;
      ob[2*HW+p] = fminf(fmaxf(r2,0.f),1.f)*255.0f;
    }
  }
  if (MODE==0) {
    __syncthreads();
    unsigned* gh = hist + (size_t)b*2048;
    for (int i=t;i<2048;i+=256){ unsigned v=hl[i]; if (v) atomicAdd(&gh[i], v); }
  }
}

// ============ radix hist levels 1/2, pick of previous level fused ============
template<int LEVEL>
__global__ __launch_bounds__(256) void k_lvl(const float* __restrict__ dark,
                                             unsigned* __restrict__ hist)
{
  __shared__ unsigned hl[2048];
  __shared__ unsigned ps[256];
  __shared__ unsigned sgab[2];
  const int t=threadIdx.x, b=blockIdx.y;
  int bin0, bin1; unsigned ab0, ab1;
  const unsigned* h0 = hist + (size_t)b*2048;
  for (int i=t;i<2048;i+=256) hl[i]=h0[i];
  __syncthreads();
  pick_bin(hl, ps, sgab, 2048, NPIX, bin0, ab0);
  unsigned pref;
  if (LEVEL==2) {
    const unsigned* h1 = hist + ((size_t)16+b)*2048;
    for (int i=t;i<2048;i+=256) hl[i]=h1[i];
    __syncthreads();
    pick_bin(hl, ps, sgab, 2048, NPIX-ab0, bin1, ab1);
    pref = ((unsigned)bin0<<11)|(unsigned)bin1;
  } else {
    pref = (unsigned)bin0;
  }
  for (int i=t;i<2048;i+=256) hl[i]=0u;
  __syncthreads();
  const uint4* db = (const uint4*)(dark + (size_t)b*HW) + (size_t)blockIdx.x*1600;
  for (int o=t;o<1600;o+=256) {
    uint4 v = db[o];
    if (LEVEL==1) {
      if((v.x>>21)==pref) atomicAdd(&hl[(v.x>>10)&0x7FFu],1u);
      if((v.y>>21)==pref) atomicAdd(&hl[(v.y>>10)&0x7FFu],1u);
      if((v.z>>21)==pref) atomicAdd(&hl[(v.z>>10)&0x7FFu],1u);
      if((v.w>>21)==pref) atomicAdd(&hl[(v.w>>10)&0x7FFu],1u);
    } else {
      if((v.x>>10)==pref) atomicAdd(&hl[v.x&0x3FFu],1u);
      if((v.y>>10)==pref) atomicAdd(&hl[v.y&0x3FFu],1u);
      if((v.z>>10)==pref) atomicAdd(&hl[v.z&0x3FFu],1u);
      if((v.w>>10)==pref) atomicAdd(&hl[v.w&0x3FFu],1u);
    }
  }
  __syncthreads();
  unsigned* gh = hist + ((size_t)(LEVEL==1?16:32)+b)*2048;
  const int nb = (LEVEL==1)?2048:1024;
  for (int i=t;i<nb;i+=256){ unsigned v=hl[i]; if (v) atomicAdd(&gh[i], v); }
}

// ============ final threshold + tie budget ============
__global__ __launch_bounds__(256) void k_pick(const unsigned* __restrict__ hist,
                                              int* __restrict__ ctrl)
{
  __shared__ unsigned hl[2048];
  __shared__ unsigned ps[256];
  __shared__ unsigned sgab[2];
  const int b=blockIdx.x, t=threadIdx.x;
  int bin0,bin1,bin2; unsigned ab0,ab1,ab2;
  const unsigned* h0 = hist + (size_t)b*2048;
  for (int i=t;i<2048;i+=256) hl[i]=h0[i];
  __syncthreads();
  pick_bin(hl, ps, sgab, 2048, NPIX, bin0, ab0);
  const unsigned* h1 = hist + ((size_t)16+b)*2048;
  for (int i=t;i<2048;i+=256) hl[i]=h1[i];
  __syncthreads();
  pick_bin(hl, ps, sgab, 2048, NPIX-ab0, bin1, ab1);
  const unsigned* h2 = hist + ((size_t)32+b)*2048;
  for (int i=t;i<1024;i+=256) hl[i]=h2[i];
  __syncthreads();
  const unsigned t2 = NPIX - ab0 - ab1;
  pick_bin(hl, ps, sgab, 1024, t2, bin2, ab2);
  if (t==0) {
    unsigned pref21 = ((unsigned)bin0<<11)|(unsigned)bin1;
    ctrl[b*8+4] = (int)((pref21<<10)|(unsigned)bin2);   // thr bits
    ctrl[b*8+5] = (int)(t2 - ab2);                      // K ties needed
  }
}

// ============ per-block tie counts (uint4) ============
__global__ __launch_bounds__(256) void k_tiecnt(const float* __restrict__ dark,
    const int* __restrict__ ctrl, unsigned* __restrict__ tieCnt)
{
  const int b=blockIdx.y, blk=blockIdx.x, t=threadIdx.x;
  const unsigned thr=(unsigned)ctrl[b*8+4];
  const uint4* db=(const uint4*)(dark+(size_t)b*HW)+(size_t)blk*400;
  unsigned cnt=0;
  for (int o=t;o<400;o+=256) {
    uint4 v=db[o];
    cnt += (v.x==thr)+(v.y==thr)+(v.z==thr)+(v.w==thr);
  }
  __shared__ unsigned red[256];
  red[t]=cnt; __syncthreads();
  for (int s=128;s>0;s>>=1){ if(t<s) red[t]+=red[t+s]; __syncthreads(); }
  if (t==0) tieCnt[b*256+blk]=red[0];
}

// ============ exclusive scan of tie counts (parallel) ============
__global__ __launch_bounds__(256) void k_tiescan(const unsigned* __restrict__ tieCnt,
                                                 unsigned* __restrict__ tieOff)
{
  const int b=blockIdx.x, t=threadIdx.x;
  __shared__ unsigned s[256];
  unsigned own = tieCnt[b*256+t];
  s[t]=own; __syncthreads();
  for (int off=1;off<256;off<<=1) {
    unsigned v=(t>=off)?s[t-off]:0u;
    __syncthreads();
    s[t]+=v;
    __syncthreads();
  }
  tieOff[b*256+t]=s[t]-own;
}

// ============ selection: strict-above max + first-K-ties-by-index ============
#define AMAX3(p) do { \
  atomicMax(&amax[b*4+0], __float_as_uint(xb[(p)])); \
  atomicMax(&amax[b*4+1], __float_as_uint(xb[HW+(p)])); \
  atomicMax(&amax[b*4+2], __float_as_uint(xb[2*HW+(p)])); } while(0)

__global__ __launch_bounds__(256) void k_select(
    const float* __restrict__ x, const float* __restrict__ dark,
    const int* __restrict__ ctrl, const unsigned* __restrict__ tieOff,
    unsigned* __restrict__ amax)
{
  const int b=blockIdx.y, blk=blockIdx.x, t=threadIdx.x;
  const unsigned thr=(unsigned)ctrl[b*8+4];
  const unsigned K  =(unsigned)ctrl[b*8+5];
  const unsigned myOff = tieOff[b*256+blk];
  const float* xb = x + (size_t)b*3*HW;
  const uint4* db = (const uint4*)(dark + (size_t)b*HW) + (size_t)blk*400;
  const unsigned base = (unsigned)blk*1600u;
  const int wave=t>>6, lane=t&63;
  __shared__ unsigned wcnt[4];
  __shared__ unsigned running;
  if (t==0) running=0u;
  __syncthreads();
  #pragma unroll
  for (int cch=0; cch<2; ++cch) {
    int o = cch*256 + t;
    bool valid = o < 400;
    uint4 v = make_uint4(0u,0u,0u,0u);
    if (valid) v = db[o];
    unsigned p0 = base + (unsigned)o*4u;
    bool eq0 = valid && (v.x==thr), eq1 = valid && (v.y==thr);
    bool eq2 = valid && (v.z==thr), eq3 = valid && (v.w==thr);
    if (valid) {                       // strictly-above: always selected
      if (v.x>thr) AMAX3(p0);
      if (v.y>thr) AMAX3(p0+1);
      if (v.z>thr) AMAX3(p0+2);
      if (v.w>thr) AMAX3(p0+3);
    }
    unsigned long long m0=__ballot(eq0), m1=__ballot(eq1);
    unsigned long long m2=__ballot(eq2), m3=__ballot(eq3);
    if (lane==0)
      wcnt[wave]=(unsigned)(__popcll(m0)+__popcll(m1)+__popcll(m2)+__popcll(m3));
    __syncthreads();
    if (eq0|eq1|eq2|eq3) {
      unsigned long long low = (1ull<<lane)-1ull;   // lane<=63 safe
      unsigned pre = (unsigned)(__popcll(m0&low)+__popcll(m1&low)
                               +__popcll(m2&low)+__popcll(m3&low));
      unsigned wpre=0;
      for (int w2=0;w2<wave;++w2) wpre += wcnt[w2];
      unsigned r = running + wpre + pre;   // ties before me (this block, index order)
      if (eq0) { if (myOff + r < K) AMAX3(p0);   ++r; }
      if (eq1) { if (myOff + r < K) AMAX3(p0+1); ++r; }
      if (eq2) { if (myOff + r < K) AMAX3(p0+2); ++r; }
      if (eq3) { if (myOff + r < K) AMAX3(p0+3); }
    }
    __syncthreads();
    if (t==0) running += wcnt[0]+wcnt[1]+wcnt[2]+wcnt[3];
    __syncthreads();
  }
}

extern "C" void kernel_launch(void* const* d_in, const int* in_sizes, int n_in,
                              void* d_out, int out_size, void* d_ws, size_t ws_size,
                              hipStream_t stream) {
  (void)in_sizes; (void)n_in; (void)out_size; (void)ws_size;
  const float* x = (const float*)d_in[0];
  float* out = (float*)d_out;
  char* ws = (char*)d_ws;
  float*    dark   = (float*)(ws + DARK_OFF);
  unsigned* hist   = (unsigned*)(ws + HIST_OFF);
  unsigned* amax   = (unsigned*)(ws + AMAX_OFF);
  int*      ctrl   = (int*)(ws + CTRL_OFF);
  unsigned* tieCnt = (unsigned*)(ws + TIECNT_OFF);
  unsigned* tieOff = (unsigned*)(ws + TIEOFF_OFF);

  hipMemsetAsync(ws + HIST_OFF, 0, ZERO_BYTES, stream);   // hist + amax

  const dim3 gt2(10, 16, B);
  const dim3 gl(64, B);
  const dim3 gs(256, B);

  k_pool<0><<<gt2, 256, 0, stream>>>(x, dark, hist, nullptr, nullptr);
  k_lvl<1><<<gl, 256, 0, stream>>>(dark, hist);
  k_lvl<2><<<gl, 256, 0, stream>>>(dark, hist);
  k_pick<<<B, 256, 0, stream>>>(hist, ctrl);
  k_tiecnt<<<gs, 256, 0, stream>>>(dark, ctrl, tieCnt);
  k_tiescan<<<B, 256, 0, stream>>>(tieCnt, tieOff);
  k_select<<<gs, 256, 0, stream>>>(x, dark, ctrl, tieOff, amax);
  k_pool<1><<<gt2, 256, 0, stream>>>(x, nullptr, nullptr, amax, out);
}